// Round 3
// baseline (79.988 us; speedup 1.0000x reference)
//
#include <hip/hip_runtime.h>
#include <hip/hip_bf16.h>

// Factorized NaiveBias2d:
//   out[n, a*32+b, h, d] = sum_e bias[h,b,e]*Vc[n,e,h,d] + sum_c bias[h,a,c]*Ve[n,c,h,d]
//   bias[h,j,i] = w[h, (32 + j - i) % 63]
//   Vc[n,e,h,d] = sum_c v[n, c*32+e, h, d]   Ve[n,c,h,d] = sum_e v[n, c*32+e, h, d]
//
// Constants: BATCH=8, SEQ=1024 (32x32), HEADS=8, DIM=64 -> hd stride 512 floats
// = 128 float4.

#define S 32
#define HD4 128   // hd extent in float4 units

// ---------------- Stage 1: reductions over c (Vc) and e (Ve) ----------------
// grid 512 blocks x 128 threads (float4 per thread over hd).
// Blocks 0..255: Vc (block=n*32+e). Blocks 256..511: Ve (block=n*32+c).
// Each wave-load is 64 lanes x 16 B = 1 KiB contiguous (coalescing sweet spot).
__global__ __launch_bounds__(128) void reduce_kernel(
    const float4* __restrict__ v, float4* __restrict__ Vc,
    float4* __restrict__ Ve) {
  int block = blockIdx.x;
  int t = threadIdx.x;                  // 0..127
  bool isVc = block < 256;
  int b2 = isVc ? block : block - 256;  // n*32 + x
  int n = b2 >> 5;
  int x = b2 & 31;                      // e for Vc, c for Ve
  const float4* base = v + (size_t)n * 1024 * HD4 + t;
  float4 acc = make_float4(0.f, 0.f, 0.f, 0.f);
  if (isVc) {
#pragma unroll
    for (int c = 0; c < 32; ++c) {
      float4 r = base[(size_t)(c * S + x) * HD4];
      acc.x += r.x; acc.y += r.y; acc.z += r.z; acc.w += r.w;
    }
    Vc[(size_t)b2 * HD4 + t] = acc;
  } else {
#pragma unroll
    for (int e = 0; e < 32; ++e) {
      float4 r = base[(size_t)(x * S + e) * HD4];
      acc.x += r.x; acc.y += r.y; acc.z += r.z; acc.w += r.w;
    }
    Ve[(size_t)b2 * HD4 + t] = acc;
  }
}

// ------------- Stage 2 (fused): terms + broadcast-add + store ---------------
// Block = (n, h, a): blockIdx = (n*8 + h)*32 + a, 2048 blocks x 256 threads.
// Stages bias + Vc/Ve (n,h)-slices in LDS, computes
//   T1[b,d] = sum_e bias[h,b,e]*Vc[n,e,h,d]   (all b, redundant across a-blocks
//                                              -- 268 MFLOP total, free)
//   T2[d]   = sum_c bias[h,a,c]*Ve[n,c,h,d]   (this block's a only)
// then writes out rows j = a*32+b as float4: out[n,j,h,d] = T1[b,d] + T2[d].
__global__ __launch_bounds__(256) void fused_out_kernel(
    const float* __restrict__ w,
    const float* __restrict__ Vc, const float* __restrict__ Ve,
    float4* __restrict__ out) {
  __shared__ float bias_s[32][32];   // bias[h, b, e]
  __shared__ float biasa_s[32];      // bias[h, a, c] (row a)
  __shared__ float vc_s[32][64];
  __shared__ float ve_s[32][64];
  __shared__ float t1_s[32][64];
  __shared__ float t2_s[64];

  int blk = blockIdx.x;
  int a  = blk & 31;
  int h  = (blk >> 5) & 7;
  int n  = blk >> 8;
  int t  = threadIdx.x;

  // bias[j][i] = w[h, (32 + j - i) % 63]
  for (int idx = t; idx < 1024; idx += 256) {
    int b = idx >> 5, e = idx & 31;
    bias_s[b][e] = w[h * 63 + (32 + b - e) % 63];
  }
  if (t < 32) biasa_s[t] = w[h * 63 + (32 + a - t) % 63];

  // Stage Vc/Ve (n,h)-slices: 32 rows x 16 float4 each.
  for (int idx = t; idx < 512; idx += 256) {
    int e = idx >> 4, d4 = idx & 15;
    size_t g = ((size_t)(n * S + e) * 8 + h) * 16 + d4;  // float4 units
    float4 va = ((const float4*)Vc)[g];
    float4 vb = ((const float4*)Ve)[g];
    vc_s[e][d4 * 4 + 0] = va.x; vc_s[e][d4 * 4 + 1] = va.y;
    vc_s[e][d4 * 4 + 2] = va.z; vc_s[e][d4 * 4 + 3] = va.w;
    ve_s[e][d4 * 4 + 0] = vb.x; ve_s[e][d4 * 4 + 1] = vb.y;
    ve_s[e][d4 * 4 + 2] = vb.z; ve_s[e][d4 * 4 + 3] = vb.w;
  }
  __syncthreads();

  int d  = t & 63;    // lanes of a wave share bg -> bias_s reads broadcast
  int bg = t >> 6;    // 0..3
  // T2 row for this a (threads of bg==0 write it; 64 lanes = one wave)
  if (t < 64) {
    float a2 = 0.f;
#pragma unroll
    for (int c = 0; c < 32; ++c) a2 += biasa_s[c] * ve_s[c][t];
    t2_s[t] = a2;
  }
  // T1 all rows
  for (int b = bg; b < 32; b += 4) {
    float a1 = 0.f;
#pragma unroll
    for (int e = 0; e < 32; ++e) a1 += bias_s[b][e] * vc_s[e][d];
    t1_s[b][d] = a1;
  }
  __syncthreads();

  // Write 32 rows x 16 float4; row j = a*32+b at out[((n*1024+j)*8+h)*16 + d4]
  const float4* t1v = (const float4*)t1_s;
  const float4* t2v = (const float4*)t2_s;
  size_t obase = ((size_t)(n * 1024 + a * 32) * 8 + h) * 16;
#pragma unroll
  for (int idx = t; idx < 512; idx += 256) {
    int b = idx >> 4, d4 = idx & 15;
    float4 x = t1v[b * 16 + d4];
    float4 y = t2v[d4];
    out[obase + (size_t)b * 128 + d4] =
        make_float4(x.x + y.x, x.y + y.y, x.z + y.z, x.w + y.w);
  }
}

extern "C" void kernel_launch(void* const* d_in, const int* in_sizes, int n_in,
                              void* d_out, int out_size, void* d_ws, size_t ws_size,
                              hipStream_t stream) {
  const float* v = (const float*)d_in[0];   // (8,1024,8,64) fp32
  const float* w = (const float*)d_in[1];   // (1,8,63)      fp32
  float* out = (float*)d_out;               // (8,1024,8,64) fp32
  float* ws  = (float*)d_ws;

  float* Vc = ws;                 // 131072 floats
  float* Ve = ws + 131072;        // 131072 floats (1 MB total)

  reduce_kernel<<<512, 128, 0, stream>>>((const float4*)v, (float4*)Vc,
                                         (float4*)Ve);
  fused_out_kernel<<<2048, 256, 0, stream>>>(w, Vc, Ve, (float4*)out);
}